// Round 13
// baseline (138.448 us; speedup 1.0000x reference)
//
#include <hip/hip_runtime.h>
#include <hip/hip_bf16.h>

#define B_N 8192
#define D_K 256
#define MARGIN 0.3f
#define NT 8256   // 128*129/2 triangular 64x64 tiles

typedef float f32x4 __attribute__((ext_vector_type(4)));
typedef short s16x8 __attribute__((ext_vector_type(8)));

__device__ __forceinline__ unsigned fkey(float f) {
    unsigned u = __float_as_uint(f);
    return (u & 0x80000000u) ? ~u : (u | 0x80000000u);
}
__device__ __forceinline__ float kval(unsigned k) {
    return (k & 0x80000000u) ? __uint_as_float(k ^ 0x80000000u)
                             : __uint_as_float(~k);
}

// async 16B global -> LDS (LDS dest = wave-uniform base + lane*16)
__device__ __forceinline__ void load_lds16(const unsigned short* g,
                                           unsigned short* l) {
    __builtin_amdgcn_global_load_lds(
        (const __attribute__((address_space(1))) unsigned int*)g,
        (__attribute__((address_space(3))) unsigned int*)l, 16, 0, 0);
}

// 16-lane DPP max/min reduction (VALU pipe); result in lane 15 of each row-16
__device__ __forceinline__ float rowred_max(float v) {
    v = fmaxf(v, __int_as_float(__builtin_amdgcn_update_dpp(
            __float_as_int(v), __float_as_int(v), 0x118, 0xF, 0xF, false)));
    v = fmaxf(v, __int_as_float(__builtin_amdgcn_update_dpp(
            __float_as_int(v), __float_as_int(v), 0x114, 0xF, 0xF, false)));
    v = fmaxf(v, __int_as_float(__builtin_amdgcn_update_dpp(
            __float_as_int(v), __float_as_int(v), 0x112, 0xF, 0xF, false)));
    v = fmaxf(v, __int_as_float(__builtin_amdgcn_update_dpp(
            __float_as_int(v), __float_as_int(v), 0x111, 0xF, 0xF, false)));
    return v;
}
__device__ __forceinline__ float rowred_min(float v) {
    v = fminf(v, __int_as_float(__builtin_amdgcn_update_dpp(
            __float_as_int(v), __float_as_int(v), 0x118, 0xF, 0xF, false)));
    v = fminf(v, __int_as_float(__builtin_amdgcn_update_dpp(
            __float_as_int(v), __float_as_int(v), 0x114, 0xF, 0xF, false)));
    v = fminf(v, __int_as_float(__builtin_amdgcn_update_dpp(
            __float_as_int(v), __float_as_int(v), 0x112, 0xF, 0xF, false)));
    v = fminf(v, __int_as_float(__builtin_amdgcn_update_dpp(
            __float_as_int(v), __float_as_int(v), 0x111, 0xF, 0xF, false)));
    return v;
}

// ---- kernel 1: bf16 round + norms OF ROUNDED VALUES + init ----------------
__global__ __launch_bounds__(256) void prep_kernel(const float* __restrict__ X,
        float* __restrict__ sq, unsigned* __restrict__ apk,
        unsigned* __restrict__ ank, unsigned short* __restrict__ Xp,
        float* __restrict__ acc2) {
    int row  = (blockIdx.x << 2) + (threadIdx.x >> 6);
    int lane = threadIdx.x & 63;
    const float4 v = reinterpret_cast<const float4*>(X + (size_t)row * D_K)[lane];

    float xs[4] = {v.x, v.y, v.z, v.w};
    ushort4 hv;
    unsigned short* hp = &hv.x;
    float s = 0.f;
    #pragma unroll
    for (int i = 0; i < 4; ++i) {
        __hip_bfloat16 h = __float2bfloat16(xs[i]);
        hp[i] = *reinterpret_cast<unsigned short*>(&h);
        float hf = __bfloat162float(h);
        s = fmaf(hf, hf, s);
    }
    *reinterpret_cast<ushort4*>(Xp + (size_t)row * D_K + lane * 4) = hv;

    #pragma unroll
    for (int o = 32; o > 0; o >>= 1) s += __shfl_down(s, o, 64);
    if (lane == 0) {
        sq[row]  = s;
        apk[row] = 0u;           // <= fkey(-inf)
        ank[row] = 0xFFFFFFFFu;  // >= fkey(+inf)
    }
    if (blockIdx.x == 0 && threadIdx.x == 0) {
        acc2[0] = 0.f; acc2[1] = 0.f;
        reinterpret_cast<unsigned*>(acc2)[2] = 0u;   // ticket counter
    }
}

// ---- kernel 2: single-wave 64x64 tiles, barrier-free LDS-DMA pipeline -----
// LDS slot of (row r, 16B-unit q): S = r*4 + (q ^ ((r>>2)&3))
//  - fragment reads (16 lanes, fixed q): 2 lanes/bank -> conflict-free
//  - DMA: inst j covers S=j*64+lane -> 16 consecutive rows, full 64B lines
__global__ __launch_bounds__(64, 2) void dist_kernel(
        const unsigned short* __restrict__ Xp,
        const int* __restrict__ tgt, const float* __restrict__ sq,
        unsigned* __restrict__ apk, unsigned* __restrict__ ank) {
    __shared__ __attribute__((aligned(16))) unsigned short Ab[2][64 * 32]; // 2x4KB
    __shared__ __attribute__((aligned(16))) unsigned short Bb[2][64 * 32]; // 2x4KB

    const int lane = threadIdx.x;       // block = 1 wave of 64
    const int fr   = lane & 15;
    const int quad = lane >> 4;
    const float INF = __int_as_float(0x7f800000);

    // triangular decode: blockIdx.x -> (bx, by), by <= bx  (128x128 tiles)
    int tt = blockIdx.x;
    int bx = (int)((sqrtf(8.f * (float)tt + 1.f) - 1.f) * 0.5f);
    while ((bx + 1) * (bx + 2) / 2 <= tt) ++bx;
    while (bx * (bx + 1) / 2 > tt) --bx;
    int by = tt - bx * (bx + 1) / 2;
    const int bm = by * 64;   // bm <= bn
    const int bn = bx * 64;

    // staging geometry: 4 DMA insts per operand per window
    const unsigned short* ag[4];
    const unsigned short* bg[4];
    int ldso[4];
    #pragma unroll
    for (int j = 0; j < 4; ++j) {
        int S = j * 64 + lane;             // 0..255
        int r = S >> 2;
        int q = (S & 3) ^ ((r >> 2) & 3);
        ag[j]   = Xp + (size_t)(bm + r) * D_K + q * 8;
        bg[j]   = Xp + (size_t)(bn + r) * D_K + q * 8;
        ldso[j] = S * 8;
    }

    // fragment LDS offsets (constant across windows)
    int afo[4], bfo[4];
    #pragma unroll
    for (int mi = 0; mi < 4; ++mi) {
        int R = mi * 16 + fr;
        afo[mi] = (R * 4 + (quad ^ ((R >> 2) & 3))) * 8;
    }
    #pragma unroll
    for (int ni = 0; ni < 4; ++ni) {
        int R = ni * 16 + fr;
        bfo[ni] = (R * 4 + (quad ^ ((R >> 2) & 3))) * 8;
    }

    f32x4 acc[4][4];
    #pragma unroll
    for (int i = 0; i < 4; ++i)
        #pragma unroll
        for (int j = 0; j < 4; ++j) acc[i][j] = (f32x4){0.f, 0.f, 0.f, 0.f};

    // prologue: window 0 -> buf 0
    #pragma unroll
    for (int j = 0; j < 4; ++j) {
        load_lds16(ag[j], &Ab[0][ldso[j]]);
        load_lds16(bg[j], &Bb[0][ldso[j]]);
    }

    #pragma unroll 1
    for (int w = 0; w < 7; ++w) {        // windows 0..6 (K=32 each)
        // prior frag reads complete before overwriting their buffer
        asm volatile("s_waitcnt lgkmcnt(0)" ::: "memory");
        const int ko = (w + 1) * 32;
        #pragma unroll
        for (int j = 0; j < 4; ++j) {    // prefetch w+1 into other buffer
            load_lds16(ag[j] + ko, &Ab[(w + 1) & 1][ldso[j]]);
            load_lds16(bg[j] + ko, &Bb[(w + 1) & 1][ldso[j]]);
        }
        // wait for window w's 8 DMAs (w+1's 8 stay in flight)
        asm volatile("s_waitcnt vmcnt(8)" ::: "memory");

        const unsigned short* At = Ab[w & 1];
        const unsigned short* Bt = Bb[w & 1];
        s16x8 a[4], b[4];
        #pragma unroll
        for (int mi = 0; mi < 4; ++mi)
            a[mi] = *reinterpret_cast<const s16x8*>(&At[afo[mi]]);
        #pragma unroll
        for (int ni = 0; ni < 4; ++ni)
            b[ni] = *reinterpret_cast<const s16x8*>(&Bt[bfo[ni]]);
        #pragma unroll
        for (int mi = 0; mi < 4; ++mi)
            #pragma unroll
            for (int ni = 0; ni < 4; ++ni)
                acc[mi][ni] = __builtin_amdgcn_mfma_f32_16x16x32_bf16(
                    a[mi], b[ni], acc[mi][ni], 0, 0, 0);
    }
    // last window (7) in buf 1
    {
        asm volatile("s_waitcnt vmcnt(0)" ::: "memory");
        const unsigned short* At = Ab[1];
        const unsigned short* Bt = Bb[1];
        s16x8 a[4], b[4];
        #pragma unroll
        for (int mi = 0; mi < 4; ++mi)
            a[mi] = *reinterpret_cast<const s16x8*>(&At[afo[mi]]);
        #pragma unroll
        for (int ni = 0; ni < 4; ++ni)
            b[ni] = *reinterpret_cast<const s16x8*>(&Bt[bfo[ni]]);
        #pragma unroll
        for (int mi = 0; mi < 4; ++mi)
            #pragma unroll
            for (int ni = 0; ni < 4; ++ni)
                acc[mi][ni] = __builtin_amdgcn_mfma_f32_16x16x32_bf16(
                    a[mi], b[ni], acc[mi][ni], 0, 0, 0);
    }

    // -------- epilogue: dist + row mining (DPP) + col mining (shfl) --------
    int   ct[4]; float csq[4];
    #pragma unroll
    for (int ni = 0; ni < 4; ++ni) {
        int c = bn + ni * 16 + fr;
        ct[ni] = tgt[c]; csq[ni] = sq[c];
    }
    float cap[4], can[4];
    #pragma unroll
    for (int ni = 0; ni < 4; ++ni) { cap[ni] = -INF; can[ni] = INF; }

    #pragma unroll
    for (int mi = 0; mi < 4; ++mi) {
        #pragma unroll
        for (int reg = 0; reg < 4; ++reg) {
            int rl = mi * 16 + quad * 4 + reg;
            int rt = tgt[bm + rl]; float rsq = sq[bm + rl];
            float rap = -INF, ran = INF;
            #pragma unroll
            for (int ni = 0; ni < 4; ++ni) {
                float d = rsq + csq[ni] - 2.f * acc[mi][ni][reg];
                bool pos = (rt == ct[ni]);
                if (pos) { rap = fmaxf(rap, d); cap[ni] = fmaxf(cap[ni], d); }
                else     { ran = fminf(ran, d); can[ni] = fminf(can[ni], d); }
            }
            rap = rowred_max(rap);
            ran = rowred_min(ran);
            if (fr == 15) {
                atomicMax(&apk[bm + rl], fkey(rap));
                atomicMin(&ank[bm + rl], fkey(ran));
            }
        }
    }
    #pragma unroll
    for (int ni = 0; ni < 4; ++ni) {
        #pragma unroll
        for (int o = 16; o < 64; o <<= 1) {
            cap[ni] = fmaxf(cap[ni], __shfl_xor(cap[ni], o, 64));
            can[ni] = fminf(can[ni], __shfl_xor(can[ni], o, 64));
        }
    }
    if (lane < 16) {
        #pragma unroll
        for (int ni = 0; ni < 4; ++ni) {
            int c = bn + ni * 16 + lane;
            atomicMax(&apk[c], fkey(cap[ni]));
            atomicMin(&ank[c], fkey(can[ni]));
        }
    }
}

// ---- kernel 3: loss/prec partial sums + last-block finalize ---------------
__global__ __launch_bounds__(256) void final_kernel(const unsigned* __restrict__ apk,
        const unsigned* __restrict__ ank, float* __restrict__ acc2,
        float* __restrict__ out) {
    __shared__ float s_sum[4], s_cnt[4];
    int i = blockIdx.x * 256 + threadIdx.x;
    float ap = kval(apk[i]);
    float an = kval(ank[i]);
    float v  = ap - an + MARGIN;
    float sum = v > 0.f ? v : 0.f;
    float cnt = an > ap ? 1.f : 0.f;
    #pragma unroll
    for (int o = 32; o > 0; o >>= 1) {
        sum += __shfl_down(sum, o, 64);
        cnt += __shfl_down(cnt, o, 64);
    }
    int wave = threadIdx.x >> 6, lane = threadIdx.x & 63;
    if (lane == 0) { s_sum[wave] = sum; s_cnt[wave] = cnt; }
    __syncthreads();
    if (threadIdx.x == 0) {
        float ts = 0.f, tc = 0.f;
        #pragma unroll
        for (int w = 0; w < 4; ++w) { ts += s_sum[w]; tc += s_cnt[w]; }
        atomicAdd(&acc2[0], ts);
        atomicAdd(&acc2[1], tc);
        __threadfence();
        unsigned ticket = atomicAdd(reinterpret_cast<unsigned*>(acc2) + 2, 1u);
        if (ticket == gridDim.x - 1) {
            float fs = atomicAdd(&acc2[0], 0.f);
            float fc = atomicAdd(&acc2[1], 0.f);
            out[0] = fs / (float)B_N;
            out[1] = fc / (float)B_N;
        }
    }
}

extern "C" void kernel_launch(void* const* d_in, const int* in_sizes, int n_in,
                              void* d_out, int out_size, void* d_ws, size_t ws_size,
                              hipStream_t stream) {
    const float* X   = (const float*)d_in[0];
    const int*   tgt = (const int*)d_in[1];

    char* ws = (char*)d_ws;
    float*          sq   = (float*)ws;                    // 32 KB
    unsigned*       apk  = (unsigned*)(ws + 32768);       // 32 KB
    unsigned*       ank  = (unsigned*)(ws + 65536);       // 32 KB
    float*          acc2 = (float*)(ws + 98304);          // 12 B
    unsigned short* Xp   = (unsigned short*)(ws + 131072);// 4 MB

    float* out = (float*)d_out;

    prep_kernel<<<B_N / 4, 256, 0, stream>>>(X, sq, apk, ank, Xp, acc2);
    dist_kernel<<<NT, 64, 0, stream>>>(Xp, tgt, sq, apk, ank);
    final_kernel<<<B_N / 256, 256, 0, stream>>>(apk, ank, acc2, out);
}